// Round 6
// baseline (3928.135 us; speedup 1.0000x reference)
//
#include <hip/hip_runtime.h>
#include <math.h>
#include <stdint.h>

// VanillaRNN, bit-exact (R9-lineage). Numerics FROZEN:
//   * z[i] = ascending-k single FMA chain k=0..255, init 0, split P: k=0..127
//     -> exact float LDS handoff (zpart) -> Q: k=128..255.
//   * z = ((W_hx*x_t) + chain) + bias_h, separately rounded, left-assoc
//   * tanh = Eigen/XLA fast-tanh WITH FMA (clamp 7.99881172180175781f)
//
// R15 — h-transport moved to the SCALAR pipe (SMEM/K$), h as SGPR operands.
//   Evidence (R9/R10/R11/R14 all fit): phase = max(LDS 6.8cyc x N_bcast,
//   VALU busy) + barrier. h via LDS broadcast loads the LDS pipe (R9 wall
//   1800cyc); h via v_readlane loads the VALU pipe 1:1 (R14: dur tracked
//   +VALU exactly). Both per-lane transports replicate a wave-UNIFORM value.
//   Fix: h[k] is uniform in z += w[k]*h[k] => SGPR operand (v_fma v,v,s,v,
//   1 SGPR read = legal). h lives in d_ws (4KB/WG, L2-resident):
//     Q: tanh -> plain global_store (write-through to L2; __syncthreads
//        drains vmcnt(0) before s_barrier => visible).
//     P/Q: 16x s_load_dwordx8 on the SMEM pipe, bursts of 8/4/4 with
//        "+s" pass-through s_waitcnt asm (dataflow ties: FMAs can't hoist
//        past the wait — rule-18 safe). s_dcache_inv at body start (same-WG
//        producers only; K$ must not serve last step's lines).
//   Per body: LDS ~2 instrs (zpart only), VALU = 128 FMA + ~15. Both old
//   walls gone; new path = L2 latency (~230, pipelined) + 512cyc serial
//   chain + tanh + barrier.
//   Transport-only: identical float values, identical op order => bit-exact.
// Skeleton unchanged (R10 lesson): literal-offset x2-unrolled STEP.
// Schedule (audited, R9): phaseA(u): P(col0,u,rp) | Q(col1,u-1,rp^1) [u>=1];
// phaseB(u): P(col1,u,rp) | Q(col0,u,rp); drain Q(col1,TT-1,0); rp=(u&1)^1.
// Workspace: 256 WGs x 2 cols x 2 parities x 256 floats = 1 MB of d_ws.

#define TT 2048
#define BB 512
#define HH 256
#define CC 10
#define KH 128   // chain half-length per thread group

typedef __attribute__((ext_vector_type(8))) int i8x;

__device__ __forceinline__ float ref_tanhf(float x)
{
    const float a1  = 4.89352455891786e-03f;
    const float a3  = 6.37261928875436e-04f;
    const float a5  = 1.48572235717979e-05f;
    const float a7  = 5.12229709037114e-08f;
    const float a9  = -8.60467152213735e-11f;
    const float a11 = 2.00018790482477e-13f;
    const float a13 = -2.76076847742355e-16f;
    const float b0  = 4.89352518554385e-03f;
    const float b2  = 2.26843463243900e-03f;
    const float b4  = 1.18534705686654e-04f;
    const float b6  = 1.19825839466702e-06f;

    const float kClamp = 7.99881172180175781f;
    const float xc = fmaxf(fminf(x, kClamp), -kClamp);
    const float x2 = __fmul_rn(xc, xc);
    float p = fmaf(x2, a13, a11);
    p = fmaf(x2, p, a9);
    p = fmaf(x2, p, a7);
    p = fmaf(x2, p, a5);
    p = fmaf(x2, p, a3);
    p = fmaf(x2, p, a1);
    p = __fmul_rn(xc, p);
    float q = fmaf(x2, b6, b4);
    q = fmaf(x2, q, b2);
    q = fmaf(x2, q, b0);
    const float r = __fdiv_rn(p, q);
    return (fabsf(x) < 0.0004f) ? x : r;
}

__global__ __launch_bounds__(512, 2)
void rnn_fwd(const float* __restrict__ x,
             const float* __restrict__ W_hx,
             const float* __restrict__ W_hh,
             const float* __restrict__ W_ph,
             const float* __restrict__ bias_h,
             const float* __restrict__ bias_p,
             float* __restrict__ out,
             float* __restrict__ ws)
{
    const int tid   = threadIdx.x;
    const int group = tid >> 8;        // 0 = P (k 0..127), 1 = Q (k 128..255)
    const int i     = tid & (HH - 1);  // hidden row
    const int b0    = blockIdx.x * 2;  // two batch columns per WG

    __shared__ __align__(16) float xls[2][TT];        // 16 KB
    __shared__ __align__(16) float zpart[2][HH];      // 2 KB

    // per-WG h region in global: [col][parity][row], 1 KB x 4 = 4 KB
    float* __restrict__ hg = ws + (size_t)blockIdx.x * (2 * 2 * HH);

    // --- stage: this thread's half-row of W_hh -> 128 regs (R9 exact) ---
    float w[KH];
    const float* __restrict__ wrow = W_hh + (size_t)i * HH + group * KH;
#pragma unroll
    for (int k = 0; k < KH; k += 4) {
        const float4 v = *reinterpret_cast<const float4*>(wrow + k);
        w[k] = v.x; w[k + 1] = v.y; w[k + 2] = v.z; w[k + 3] = v.w;
    }
#pragma unroll
    for (int k = 0; k < KH; ++k) {
        asm volatile("" : "+v"(w[k]));   // block rematerialization
    }

    // --- stage: x rows (2*TT contiguous floats) -> LDS, 512 threads ---
    {
        const float4* __restrict__ xsrc =
            reinterpret_cast<const float4*>(x + (size_t)b0 * TT);
        float4* __restrict__ xdst = reinterpret_cast<float4*>(&xls[0][0]);
        xdst[tid]       = xsrc[tid];
        xdst[512 + tid] = xsrc[512 + tid];
    }
    const float whx = W_hx[i];     // used by Q only
    const float bh  = bias_h[i];   // used by Q only

    // h(-1)=0 at parity 1 (step t reads (t&1)^1, writes t&1)
    hg[(group * 2 + 1) * HH + i] = 0.0f;   // col=group, par=1, row=i
    __syncthreads();                       // drains vmcnt(0) -> zeros in L2

// K$ invalidate: this phase reads h written last phase (same WG, via L2).
#define KINV asm volatile("s_dcache_inv\n\ts_waitcnt lgkmcnt(0)" ::: "memory")

// one s_load_dwordx8 at literal byte offset IMM from wave-uniform base hb
#define SL(DST, IMM)                                                          \
    asm volatile("s_load_dwordx8 %0, %1, " IMM                                \
                 : "=s"(DST) : "s"(hb) : "memory")

// wait with pass-through defs: consumers of A..H depend on this asm,
// so the compiler cannot hoist FMAs above the wait (rule-18 safe).
#define WAIT8(A, B, C, D, E, F, G, H)                                         \
    asm volatile("s_waitcnt lgkmcnt(0)"                                       \
                 : "+s"(A), "+s"(B), "+s"(C), "+s"(D),                        \
                   "+s"(E), "+s"(F), "+s"(G), "+s"(H))

// 8 chain FMAs; h element is a wave-uniform SGPR operand (ascending k).
#define FMA8(MT, K)                                                           \
    z = fmaf(w[(K) + 0], __int_as_float(MT[0]), z);                           \
    z = fmaf(w[(K) + 1], __int_as_float(MT[1]), z);                           \
    z = fmaf(w[(K) + 2], __int_as_float(MT[2]), z);                           \
    z = fmaf(w[(K) + 3], __int_as_float(MT[3]), z);                           \
    z = fmaf(w[(K) + 4], __int_as_float(MT[4]), z);                           \
    z = fmaf(w[(K) + 5], __int_as_float(MT[5]), z);                           \
    z = fmaf(w[(K) + 6], __int_as_float(MT[6]), z);                           \
    z = fmaf(w[(K) + 7], __int_as_float(MT[7]), z);

// P half-chain: k = 0..127 (bytes 0x000-0x1FF of h vector), init 0.
#define PBODY(COL, T, RP)                                                     \
    {                                                                         \
        KINV;                                                                 \
        const uint64_t hb =                                                   \
            (uint64_t)(uintptr_t)(hg + ((COL) * 2 + (RP)) * HH);              \
        i8x m0, m1, m2, m3, m4, m5, m6, m7;                                   \
        i8x m8, m9, m10, m11, m12, m13, m14, m15;                             \
        SL(m0, "0x00");  SL(m1, "0x20");  SL(m2, "0x40");  SL(m3, "0x60");    \
        SL(m4, "0x80");  SL(m5, "0xA0");  SL(m6, "0xC0");  SL(m7, "0xE0");    \
        float z = 0.0f;                                                       \
        WAIT8(m0, m1, m2, m3, m4, m5, m6, m7);                                \
        FMA8(m0, 0)   FMA8(m1, 8)   FMA8(m2, 16)  FMA8(m3, 24)                \
        SL(m8, "0x100");  SL(m9, "0x120");                                    \
        SL(m10, "0x140"); SL(m11, "0x160");                                   \
        FMA8(m4, 32)  FMA8(m5, 40)  FMA8(m6, 48)  FMA8(m7, 56)                \
        SL(m12, "0x180"); SL(m13, "0x1A0");                                   \
        SL(m14, "0x1C0"); SL(m15, "0x1E0");                                   \
        WAIT8(m8, m9, m10, m11, m12, m13, m14, m15);                          \
        FMA8(m8, 64)  FMA8(m9, 72)  FMA8(m10, 80)  FMA8(m11, 88)              \
        FMA8(m12, 96) FMA8(m13, 104) FMA8(m14, 112) FMA8(m15, 120)            \
        zpart[(COL)][i] = z;                                                  \
    }

// Q half-chain: k = 128..255 (bytes 0x200-0x3FF), resume from zpart,
// then x/bias/tanh, plain global_store at parity RP^1.
#define QBODY(COL, T, RP)                                                     \
    {                                                                         \
        KINV;                                                                 \
        const uint64_t hb =                                                   \
            (uint64_t)(uintptr_t)(hg + ((COL) * 2 + (RP)) * HH);              \
        i8x m0, m1, m2, m3, m4, m5, m6, m7;                                   \
        i8x m8, m9, m10, m11, m12, m13, m14, m15;                             \
        SL(m0, "0x200"); SL(m1, "0x220"); SL(m2, "0x240"); SL(m3, "0x260");   \
        SL(m4, "0x280"); SL(m5, "0x2A0"); SL(m6, "0x2C0"); SL(m7, "0x2E0");   \
        float z = zpart[(COL)][i];                                            \
        WAIT8(m0, m1, m2, m3, m4, m5, m6, m7);                                \
        FMA8(m0, 0)   FMA8(m1, 8)   FMA8(m2, 16)  FMA8(m3, 24)                \
        SL(m8, "0x300");  SL(m9, "0x320");                                    \
        SL(m10, "0x340"); SL(m11, "0x360");                                   \
        FMA8(m4, 32)  FMA8(m5, 40)  FMA8(m6, 48)  FMA8(m7, 56)                \
        SL(m12, "0x380"); SL(m13, "0x3A0");                                   \
        SL(m14, "0x3C0"); SL(m15, "0x3E0");                                   \
        WAIT8(m8, m9, m10, m11, m12, m13, m14, m15);                          \
        FMA8(m8, 64)  FMA8(m9, 72)  FMA8(m10, 80)  FMA8(m11, 88)              \
        FMA8(m12, 96) FMA8(m13, 104) FMA8(m14, 112) FMA8(m15, 120)            \
        const float a0 = __fmul_rn(whx, xls[(COL)][(T)]);                     \
        z = __fadd_rn(__fadd_rn(a0, z), bh);                                  \
        hg[((COL) * 2 + ((RP) ^ 1)) * HH + i] = ref_tanhf(z);                 \
    }

// One u-iteration with compile-time read-parity RP = (u&1)^1.
#define STEP(U, RP)                                                           \
    {                                                                         \
        if (group == 0) { PBODY(0, (U), (RP)) }                               \
        else if ((U) >= 1) { QBODY(1, (U) - 1, (RP) ^ 1) }                    \
        __syncthreads();                                                      \
        if (group == 0) { PBODY(1, (U), (RP)) }                               \
        else { QBODY(0, (U), (RP)) }                                          \
        __syncthreads();                                                      \
    }

    // u=0 peeled (resolves the u>=1 guard), then pairs with constant parity.
    STEP(0, 1)
    for (int u = 1; u + 1 < TT; u += 2) {
        STEP(u, 0)
        STEP(u + 1, 1)
    }
    STEP(TT - 1, 0)                       // u = 2047 (odd -> rp = 0)
    if (group == 1) { QBODY(1, TT - 1, 0) }   // drain pipeline: col1, last step
    __syncthreads();

#undef STEP
#undef QBODY
#undef PBODY
#undef FMA8
#undef WAIT8
#undef SL
#undef KINV

    // epilogue: p[b,c] = sum_k h_T[k]*W_ph[c,k] + bias_p[c]
    // last step t = TT-1 wrote parity (TT-1)&1 = 1; read h from global
    // (same-CU L1/L2 path; stores drained by the final __syncthreads).
    if (tid < 2 * CC) {
        const int col = tid / CC;
        const int c   = tid % CC;
        const float* __restrict__ wp = W_ph + (size_t)c * HH;
        const float* __restrict__ hf = hg + (col * 2 + 1) * HH;
        float pv = 0.0f;
#pragma unroll 8
        for (int k = 0; k < HH; ++k) {
            pv = fmaf(hf[k], wp[k], pv);
        }
        out[(size_t)(b0 + col) * CC + c] = __fadd_rn(pv, bias_p[c]);
    }
}

extern "C" void kernel_launch(void* const* d_in, const int* in_sizes, int n_in,
                              void* d_out, int out_size, void* d_ws, size_t ws_size,
                              hipStream_t stream) {
    const float* x      = (const float*)d_in[0];
    const float* W_hx   = (const float*)d_in[1];
    const float* W_hh   = (const float*)d_in[2];
    const float* W_ph   = (const float*)d_in[3];
    const float* bias_h = (const float*)d_in[4];
    const float* bias_p = (const float*)d_in[5];
    float* out = (float*)d_out;
    float* ws  = (float*)d_ws;   // needs 256 WGs * 1024 floats * 4B = 1 MB

    rnn_fwd<<<dim3(BB / 2), dim3(512), 0, stream>>>(x, W_hx, W_hh, W_ph,
                                                    bias_h, bias_p, out, ws);
}

// Round 7
// 3289.250 us; speedup vs baseline: 1.1942x; 1.1942x over previous
//
#include <hip/hip_runtime.h>
#include <math.h>
#include <stdint.h>

// VanillaRNN, bit-exact (R9-lineage). Numerics FROZEN:
//   * z[i] = ascending-k single FMA chain k=0..255, init 0, split P: k=0..127
//     -> exact float LDS handoff (zpart) -> Q: k=128..255.
//   * z = ((W_hx*x_t) + chain) + bias_h, separately rounded, left-assoc
//   * tanh = Eigen/XLA fast-tanh WITH FMA (clamp 7.99881172180175781f)
//
// R16 — three-pipe balance: h transport split LDS(48) + SMEM(80).
//   Model fit to R9/R14/R15:
//     phase = max(LDS 6.8cyc*N_bcast, VALU busy, SMEM serial latency) + barrier
//   R9  pure-LDS:  LDS 1800 cyc wall (264 bcast/phase)     -> 3072us
//   R14 LDS+RL:    VALU 2300 wall (readlane = VALU 1:1)    -> 3916us
//   R15 pure-SMEM: latency 2300 wall (inv+L2 RT exposed,
//                  VALUBusy 51%, LDS conflicts 0)          -> 3928us
//   Fix: k=0..47 via LDS broadcast (12 ds_read_b128/body, pipe ~710cyc/CU),
//   k=48..127 via 10 s_load_dwordx8 issued at body TOP so the L2 round trip
//   hides under the 48 LDS-FMAs (~340cyc of cover). Q stores tanh to BOTH
//   hbuf (LDS half) and hg (global, SMEM half). All pipes ~1/3-1/2 loaded.
//   Transport-only: same float values, same ascending-k order => bit-exact.
// Skeleton = R9 verbatim (R10 lesson: literal-offset x2-unrolled STEP).
// Schedule (audited): phaseA(u): P(col0,u,rp) | Q(col1,u-1,rp^1) [u>=1];
// phaseB(u): P(col1,u,rp) | Q(col0,u,rp); drain Q(col1,TT-1,0); rp=(u&1)^1.
// Workspace: 256 WGs x 2 cols x 2 parities x 256 floats = 1 MB of d_ws.

#define TT 2048
#define BB 512
#define HH 256
#define CC 10
#define KH 128   // chain half-length per thread group

typedef __attribute__((ext_vector_type(8))) int i8x;

__device__ __forceinline__ float ref_tanhf(float x)
{
    const float a1  = 4.89352455891786e-03f;
    const float a3  = 6.37261928875436e-04f;
    const float a5  = 1.48572235717979e-05f;
    const float a7  = 5.12229709037114e-08f;
    const float a9  = -8.60467152213735e-11f;
    const float a11 = 2.00018790482477e-13f;
    const float a13 = -2.76076847742355e-16f;
    const float b0  = 4.89352518554385e-03f;
    const float b2  = 2.26843463243900e-03f;
    const float b4  = 1.18534705686654e-04f;
    const float b6  = 1.19825839466702e-06f;

    const float kClamp = 7.99881172180175781f;
    const float xc = fmaxf(fminf(x, kClamp), -kClamp);
    const float x2 = __fmul_rn(xc, xc);
    float p = fmaf(x2, a13, a11);
    p = fmaf(x2, p, a9);
    p = fmaf(x2, p, a7);
    p = fmaf(x2, p, a5);
    p = fmaf(x2, p, a3);
    p = fmaf(x2, p, a1);
    p = __fmul_rn(xc, p);
    float q = fmaf(x2, b6, b4);
    q = fmaf(x2, q, b2);
    q = fmaf(x2, q, b0);
    const float r = __fdiv_rn(p, q);
    return (fabsf(x) < 0.0004f) ? x : r;
}

__global__ __launch_bounds__(512, 2)
void rnn_fwd(const float* __restrict__ x,
             const float* __restrict__ W_hx,
             const float* __restrict__ W_hh,
             const float* __restrict__ W_ph,
             const float* __restrict__ bias_h,
             const float* __restrict__ bias_p,
             float* __restrict__ out,
             float* __restrict__ ws)
{
    const int tid   = threadIdx.x;
    const int group = tid >> 8;        // 0 = P (k 0..127), 1 = Q (k 128..255)
    const int i     = tid & (HH - 1);  // hidden row
    const int b0    = blockIdx.x * 2;  // two batch columns per WG

    __shared__ __align__(16) float xls[2][TT];        // 16 KB
    __shared__ __align__(16) float hbuf[2][2][HH];    // [col][parity][row] 4 KB
    __shared__ __align__(16) float zpart[2][HH];      // 2 KB

    // per-WG h region in global: [col][parity][row], 4 KB (SMEM half source)
    float* __restrict__ hg = ws + (size_t)blockIdx.x * (2 * 2 * HH);

    // --- stage: this thread's half-row of W_hh -> 128 regs (R9 exact) ---
    float w[KH];
    const float* __restrict__ wrow = W_hh + (size_t)i * HH + group * KH;
#pragma unroll
    for (int k = 0; k < KH; k += 4) {
        const float4 v = *reinterpret_cast<const float4*>(wrow + k);
        w[k] = v.x; w[k + 1] = v.y; w[k + 2] = v.z; w[k + 3] = v.w;
    }
#pragma unroll
    for (int k = 0; k < KH; ++k) {
        asm volatile("" : "+v"(w[k]));   // block rematerialization
    }

    // --- stage: x rows (2*TT contiguous floats) -> LDS, 512 threads ---
    {
        const float4* __restrict__ xsrc =
            reinterpret_cast<const float4*>(x + (size_t)b0 * TT);
        float4* __restrict__ xdst = reinterpret_cast<float4*>(&xls[0][0]);
        xdst[tid]       = xsrc[tid];
        xdst[512 + tid] = xsrc[512 + tid];
    }
    const float whx = W_hx[i];     // used by Q only
    const float bh  = bias_h[i];   // used by Q only

    // h(-1)=0 at parity 1 in BOTH stores (step t reads (t&1)^1, writes t&1)
    hbuf[group][1][i] = 0.0f;                // col=group, par=1, row=i
    hg[(group * 2 + 1) * HH + i] = 0.0f;
    __syncthreads();                         // drains lgkm + vmcnt(0)

// K$ invalidate: SMEM half reads hg written last phase (same WG, via L2).
#define KINV asm volatile("s_dcache_inv\n\ts_waitcnt lgkmcnt(0)" ::: "memory")

// one s_load_dwordx8 at literal byte offset IMM from wave-uniform base hb
#define SL(DST, IMM)                                                          \
    asm volatile("s_load_dwordx8 %0, %1, " IMM                                \
                 : "=s"(DST) : "s"(hb) : "memory")

// wait with pass-through defs: consumers of A..J depend on this asm,
// so the compiler cannot hoist SMEM-FMAs above the wait (rule-18 safe).
#define WAIT10(A, B, C, D, E, F, G, H, I, J)                                  \
    asm volatile("s_waitcnt lgkmcnt(0)"                                       \
                 : "+s"(A), "+s"(B), "+s"(C), "+s"(D), "+s"(E),               \
                   "+s"(F), "+s"(G), "+s"(H), "+s"(I), "+s"(J))

// 4 chain FMAs, h via broadcast ds_read_b128 at literal offset HB+KL.
#define BC4(KL, HB)                                                           \
    {                                                                         \
        const float4 h4 = *reinterpret_cast<const float4*>(h + (HB) + (KL));  \
        z = fmaf(w[(KL) + 0], h4.x, z);                                       \
        z = fmaf(w[(KL) + 1], h4.y, z);                                       \
        z = fmaf(w[(KL) + 2], h4.z, z);                                       \
        z = fmaf(w[(KL) + 3], h4.w, z);                                       \
    }
#define BC48(HB)                                                              \
    BC4(0, HB)  BC4(4, HB)  BC4(8, HB)  BC4(12, HB)                           \
    BC4(16, HB) BC4(20, HB) BC4(24, HB) BC4(28, HB)                           \
    BC4(32, HB) BC4(36, HB) BC4(40, HB) BC4(44, HB)

// 8 chain FMAs; h element is a wave-uniform SGPR operand (ascending k).
#define FMA8(MT, K)                                                           \
    z = fmaf(w[(K) + 0], __int_as_float(MT[0]), z);                           \
    z = fmaf(w[(K) + 1], __int_as_float(MT[1]), z);                           \
    z = fmaf(w[(K) + 2], __int_as_float(MT[2]), z);                           \
    z = fmaf(w[(K) + 3], __int_as_float(MT[3]), z);                           \
    z = fmaf(w[(K) + 4], __int_as_float(MT[4]), z);                           \
    z = fmaf(w[(K) + 5], __int_as_float(MT[5]), z);                           \
    z = fmaf(w[(K) + 6], __int_as_float(MT[6]), z);                           \
    z = fmaf(w[(K) + 7], __int_as_float(MT[7]), z);

#define FMA80                                                                 \
    FMA8(m0, 48)  FMA8(m1, 56)  FMA8(m2, 64)  FMA8(m3, 72)  FMA8(m4, 80)     \
    FMA8(m5, 88)  FMA8(m6, 96)  FMA8(m7, 104) FMA8(m8, 112) FMA8(m9, 120)

// P half-chain: k = 0..47 via LDS, k = 48..127 via SMEM (bytes 0xC0-0x1FF).
#define PBODY(COL, T, RP)                                                     \
    {                                                                         \
        KINV;                                                                 \
        const uint64_t hb =                                                   \
            (uint64_t)(uintptr_t)(hg + ((COL) * 2 + (RP)) * HH);              \
        i8x m0, m1, m2, m3, m4, m5, m6, m7, m8, m9;                           \
        SL(m0, "0xC0");  SL(m1, "0xE0");  SL(m2, "0x100"); SL(m3, "0x120");   \
        SL(m4, "0x140"); SL(m5, "0x160"); SL(m6, "0x180"); SL(m7, "0x1A0");   \
        SL(m8, "0x1C0"); SL(m9, "0x1E0");                                     \
        const float* __restrict__ h = &hbuf[(COL)][(RP)][0];                  \
        float z = 0.0f;                                                       \
        BC48(0)                                                               \
        WAIT10(m0, m1, m2, m3, m4, m5, m6, m7, m8, m9);                       \
        FMA80                                                                 \
        zpart[(COL)][i] = z;                                                  \
    }

// Q half-chain: k = 128..175 via LDS (hbuf+128), k = 176..255 via SMEM
// (bytes 0x2C0-0x3FF); then x/bias/tanh, store BOTH hbuf and hg at RP^1.
#define QBODY(COL, T, RP)                                                     \
    {                                                                         \
        KINV;                                                                 \
        const uint64_t hb =                                                   \
            (uint64_t)(uintptr_t)(hg + ((COL) * 2 + (RP)) * HH);              \
        i8x m0, m1, m2, m3, m4, m5, m6, m7, m8, m9;                           \
        SL(m0, "0x2C0"); SL(m1, "0x2E0"); SL(m2, "0x300"); SL(m3, "0x320");   \
        SL(m4, "0x340"); SL(m5, "0x360"); SL(m6, "0x380"); SL(m7, "0x3A0");   \
        SL(m8, "0x3C0"); SL(m9, "0x3E0");                                     \
        const float* __restrict__ h = &hbuf[(COL)][(RP)][0];                  \
        float z = zpart[(COL)][i];                                            \
        BC48(KH)                                                              \
        WAIT10(m0, m1, m2, m3, m4, m5, m6, m7, m8, m9);                       \
        FMA80                                                                 \
        const float a0 = __fmul_rn(whx, xls[(COL)][(T)]);                     \
        z = __fadd_rn(__fadd_rn(a0, z), bh);                                  \
        const float hv = ref_tanhf(z);                                        \
        hbuf[(COL)][(RP) ^ 1][i] = hv;                                        \
        hg[((COL) * 2 + ((RP) ^ 1)) * HH + i] = hv;                           \
    }

// One u-iteration with compile-time read-parity RP = (u&1)^1.
#define STEP(U, RP)                                                           \
    {                                                                         \
        if (group == 0) { PBODY(0, (U), (RP)) }                               \
        else if ((U) >= 1) { QBODY(1, (U) - 1, (RP) ^ 1) }                    \
        __syncthreads();                                                      \
        if (group == 0) { PBODY(1, (U), (RP)) }                               \
        else { QBODY(0, (U), (RP)) }                                          \
        __syncthreads();                                                      \
    }

    // u=0 peeled (resolves the u>=1 guard), then pairs with constant parity.
    STEP(0, 1)
    for (int u = 1; u + 1 < TT; u += 2) {
        STEP(u, 0)
        STEP(u + 1, 1)
    }
    STEP(TT - 1, 0)                       // u = 2047 (odd -> rp = 0)
    if (group == 1) { QBODY(1, TT - 1, 0) }   // drain pipeline: col1, last step
    __syncthreads();

#undef STEP
#undef QBODY
#undef PBODY
#undef FMA80
#undef FMA8
#undef BC48
#undef BC4
#undef WAIT10
#undef SL
#undef KINV

    // epilogue: p[b,c] = sum_k h_T[k]*W_ph[c,k] + bias_p[c]
    // last step t = TT-1 wrote parity (TT-1)&1 = 1; full h is in LDS hbuf.
    if (tid < 2 * CC) {
        const int col = tid / CC;
        const int c   = tid % CC;
        const float* __restrict__ wp = W_ph + (size_t)c * HH;
        const float* __restrict__ hf = hbuf[col][1];
        float pv = 0.0f;
#pragma unroll 8
        for (int k = 0; k < HH; ++k) {
            pv = fmaf(hf[k], wp[k], pv);
        }
        out[(size_t)(b0 + col) * CC + c] = __fadd_rn(pv, bias_p[c]);
    }
}

extern "C" void kernel_launch(void* const* d_in, const int* in_sizes, int n_in,
                              void* d_out, int out_size, void* d_ws, size_t ws_size,
                              hipStream_t stream) {
    const float* x      = (const float*)d_in[0];
    const float* W_hx   = (const float*)d_in[1];
    const float* W_hh   = (const float*)d_in[2];
    const float* W_ph   = (const float*)d_in[3];
    const float* bias_h = (const float*)d_in[4];
    const float* bias_p = (const float*)d_in[5];
    float* out = (float*)d_out;
    float* ws  = (float*)d_ws;   // 256 WGs * 1024 floats * 4B = 1 MB

    rnn_fwd<<<dim3(BB / 2), dim3(512), 0, stream>>>(x, W_hx, W_hh, W_ph,
                                                    bias_h, bias_p, out, ws);
}